// Round 4
// baseline (594.379 us; speedup 1.0000x reference)
//
#include <hip/hip_runtime.h>
#include <hip/hip_bf16.h>
#include <hip/hip_fp16.h>

#define NDIM_IN 128
#define HID 64
#define NS 8  // dst-space slices == XCD count; blockIdx%8 co-locates per XCD

// ---------------------------------------------------------------------------
// Sliced degree count: block b owns dst slice (b % NS); scans edge chunk
// (b / NS) with int4 loads. Atomics on cnt stay XCD-local.
// ---------------------------------------------------------------------------
__global__ __launch_bounds__(256) void count_deg(const int* __restrict__ dst,
                                                 int* __restrict__ cnt, int E,
                                                 int slice_sz, int nchunks) {
  int s = blockIdx.x % NS;
  int c = blockIdx.x / NS;
  int lo = s * slice_sz, hi = lo + slice_sz;
  int E4 = E >> 2;  // E divisible by 4
  int chunk4 = (E4 + nchunks - 1) / nchunks;
  int beg = c * chunk4;
  int end = min(E4, beg + chunk4);
  const int4* __restrict__ d4p = (const int4*)dst;
  for (int i = beg + (int)threadIdx.x; i < end; i += 256) {
    int4 d = d4p[i];
    if (d.x >= lo && d.x < hi) atomicAdd(&cnt[d.x], 1);
    if (d.y >= lo && d.y < hi) atomicAdd(&cnt[d.y], 1);
    if (d.z >= lo && d.z < hi) atomicAdd(&cnt[d.z], 1);
    if (d.w >= lo && d.w < hi) atomicAdd(&cnt[d.w], 1);
  }
}

__global__ __launch_bounds__(256) void make_dinv(const int* __restrict__ cnt,
                                                 float* __restrict__ dinv, int n) {
  int i = blockIdx.x * 256 + threadIdx.x;
  if (i < n) dinv[i] = rsqrtf((float)cnt[i] + 1.0f);  // +1 = self loop
}

// ---------------------------------------------------------------------------
// Exclusive scan of cnt -> rowptr (3-kernel hierarchical scan, n <= 512*256)
// ---------------------------------------------------------------------------
__global__ __launch_bounds__(256) void scan1(const int* __restrict__ cnt,
                                             int* __restrict__ rp,
                                             int* __restrict__ bs, int n) {
  __shared__ int s[256];
  int t = threadIdx.x;
  int i = blockIdx.x * 256 + t;
  int v = (i < n) ? cnt[i] : 0;
  s[t] = v;
  __syncthreads();
  for (int off = 1; off < 256; off <<= 1) {
    int x = (t >= off) ? s[t - off] : 0;
    __syncthreads();
    s[t] += x;
    __syncthreads();
  }
  if (i < n) rp[i] = s[t] - v;
  if (t == 255) bs[blockIdx.x] = s[255];
}

__global__ __launch_bounds__(512) void scan2(int* __restrict__ bs, int nb) {
  __shared__ int s[512];
  int t = threadIdx.x;
  int v = (t < nb) ? bs[t] : 0;
  s[t] = v;
  __syncthreads();
  for (int off = 1; off < 512; off <<= 1) {
    int x = (t >= off) ? s[t - off] : 0;
    __syncthreads();
    s[t] += x;
    __syncthreads();
  }
  if (t < nb) bs[t] = s[t] - v;
}

__global__ __launch_bounds__(256) void scan3(int* __restrict__ rp,
                                             const int* __restrict__ boff,
                                             int* __restrict__ pos, int n, int E) {
  int i = blockIdx.x * 256 + threadIdx.x;
  if (i < n) {
    int v = rp[i] + boff[blockIdx.x];
    rp[i] = v;
    pos[i] = v;
  }
  if (i == 0) rp[n] = E;
}

// ---------------------------------------------------------------------------
// Sliced CSR fill: block b owns dst slice (b % NS), scans edge chunk (b / NS)
// with int4 loads. pos cursors + col lines for a slice stay XCD-local.
// ---------------------------------------------------------------------------
__global__ __launch_bounds__(256) void fill_csr(const int* __restrict__ src,
                                                const int* __restrict__ dst,
                                                int* __restrict__ pos,
                                                int* __restrict__ col, int E,
                                                int slice_sz, int nchunks) {
  int s = blockIdx.x % NS;
  int c = blockIdx.x / NS;
  int lo = s * slice_sz, hi = lo + slice_sz;
  int E4 = E >> 2;
  int chunk4 = (E4 + nchunks - 1) / nchunks;
  int beg = c * chunk4;
  int end = min(E4, beg + chunk4);
  const int4* __restrict__ d4p = (const int4*)dst;
  const int4* __restrict__ s4p = (const int4*)src;
  for (int i = beg + (int)threadIdx.x; i < end; i += 256) {
    int4 d = d4p[i];
    int4 sv = s4p[i];
    if (d.x >= lo && d.x < hi) { int p = atomicAdd(&pos[d.x], 1); col[p] = sv.x; }
    if (d.y >= lo && d.y < hi) { int p = atomicAdd(&pos[d.y], 1); col[p] = sv.y; }
    if (d.z >= lo && d.z < hi) { int p = atomicAdd(&pos[d.z], 1); col[p] = sv.z; }
    if (d.w >= lo && d.w < hi) { int p = atomicAdd(&pos[d.w], 1); col[p] = sv.w; }
  }
}

// ---------------------------------------------------------------------------
// Dense transform T' = (X @ W) * dinv[row], output fp16 (halves gather bytes)
// dinv fold: msg(s->d) = T[s]*dinv[s]*dinv[d]  =>  agg[d] = dinv[d]*Σ T'[col]
// ---------------------------------------------------------------------------
template <int K>
__global__ __launch_bounds__(256) void gemm_xw(const float* __restrict__ X,
                                               const float* __restrict__ W,
                                               const float* __restrict__ dinv,
                                               __half* __restrict__ T, int n) {
  __shared__ float Ws[K * 64];
  for (int i = threadIdx.x; i < K * 64; i += 256) Ws[i] = W[i];
  __syncthreads();
  int node = blockIdx.x * 256 + threadIdx.x;
  if (node >= n) return;
  float4 acc[16];
#pragma unroll
  for (int j = 0; j < 16; j++) acc[j] = make_float4(0.f, 0.f, 0.f, 0.f);
  const float4* __restrict__ xr = (const float4*)(X + (size_t)node * K);
#pragma unroll
  for (int kc = 0; kc < K / 4; kc++) {
    float4 xv = xr[kc];
    float xs[4] = {xv.x, xv.y, xv.z, xv.w};
#pragma unroll
    for (int kk = 0; kk < 4; kk++) {
      float xk = xs[kk];
      const float4* wr = (const float4*)(Ws + (kc * 4 + kk) * 64);
#pragma unroll
      for (int j = 0; j < 16; j++) {
        float4 w = wr[j];
        acc[j].x += xk * w.x;
        acc[j].y += xk * w.y;
        acc[j].z += xk * w.z;
        acc[j].w += xk * w.w;
      }
    }
  }
  float di = dinv[node];
  uint2* __restrict__ o = (uint2*)(T + (size_t)node * 64);
#pragma unroll
  for (int j = 0; j < 16; j++) {
    __half2 h01 = __floats2half2_rn(acc[j].x * di, acc[j].y * di);
    __half2 h23 = __floats2half2_rn(acc[j].z * di, acc[j].w * di);
    uint2 pk;
    pk.x = *(unsigned int*)&h01;
    pk.y = *(unsigned int*)&h23;
    o[j] = pk;
  }
}

// ---------------------------------------------------------------------------
// SpMM gather (fp16 rows): H[v] = relu(dinv[v]*(T'[v] + Σ T'[col[e]]) + b)
// wave-per-node, lane = feature (HID==64==wavefront); 2B/lane per edge.
// ---------------------------------------------------------------------------
__global__ __launch_bounds__(256) void spmm_relu(const int* __restrict__ rp,
                                                 const int* __restrict__ col,
                                                 const __half* __restrict__ T,
                                                 const float* __restrict__ dinv,
                                                 const float* __restrict__ bias,
                                                 float* __restrict__ H, int n) {
  int gid = blockIdx.x * 256 + threadIdx.x;
  int v = gid >> 6;
  int lane = gid & 63;
  if (v >= n) return;
  int beg = rp[v], end = rp[v + 1];
  float acc0 = __half2float(T[(size_t)v * HID + lane]);  // self loop
  float acc1 = 0.f, acc2 = 0.f, acc3 = 0.f;
  int e = beg;
  for (; e + 4 <= end; e += 4) {
    int s0 = col[e], s1 = col[e + 1], s2 = col[e + 2], s3 = col[e + 3];
    acc0 += __half2float(T[(size_t)s0 * HID + lane]);
    acc1 += __half2float(T[(size_t)s1 * HID + lane]);
    acc2 += __half2float(T[(size_t)s2 * HID + lane]);
    acc3 += __half2float(T[(size_t)s3 * HID + lane]);
  }
  for (; e < end; e++) acc0 += __half2float(T[(size_t)col[e] * HID + lane]);
  float r = dinv[v] * (acc0 + acc1 + acc2 + acc3) + bias[lane];
  H[(size_t)v * HID + lane] = r > 0.f ? r : 0.f;
}

// ---------------------------------------------------------------------------
// Fused MLP head: out = relu(H @ Wp1 + bp1) @ Wp2 + bp2, thread-per-node
// ---------------------------------------------------------------------------
__global__ __launch_bounds__(256) void mlp_head(const float* __restrict__ H,
                                                const float* __restrict__ Wp1,
                                                const float* __restrict__ bp1,
                                                const float* __restrict__ Wp2,
                                                const float* __restrict__ bp2,
                                                float* __restrict__ out, int n) {
  __shared__ float W1t[32 * 64];  // transposed: W1t[j*64+k] = Wp1[k*32+j]
  __shared__ float w2s[32];
  __shared__ float b1s[32];
  for (int i = threadIdx.x; i < 64 * 32; i += 256) {
    int k = i >> 5, j = i & 31;
    W1t[j * 64 + k] = Wp1[i];
  }
  if (threadIdx.x < 32) {
    w2s[threadIdx.x] = Wp2[threadIdx.x];
    b1s[threadIdx.x] = bp1[threadIdx.x];
  }
  __syncthreads();
  int node = blockIdx.x * 256 + threadIdx.x;
  if (node >= n) return;
  float4 h[16];
  const float4* __restrict__ hr = (const float4*)(H + (size_t)node * 64);
#pragma unroll
  for (int j = 0; j < 16; j++) h[j] = hr[j];
  float o = bp2[0];
#pragma unroll
  for (int j = 0; j < 32; j++) {
    const float4* wr = (const float4*)(W1t + j * 64);
    float4 a4 = make_float4(0.f, 0.f, 0.f, 0.f);
#pragma unroll
    for (int k = 0; k < 16; k++) {
      float4 w = wr[k];
      a4.x += h[k].x * w.x;
      a4.y += h[k].y * w.y;
      a4.z += h[k].z * w.z;
      a4.w += h[k].w * w.w;
    }
    float a = a4.x + a4.y + a4.z + a4.w + b1s[j];
    a = a > 0.f ? a : 0.f;
    o += a * w2s[j];
  }
  out[node] = o;
}

// ---------------------------------------------------------------------------
extern "C" void kernel_launch(void* const* d_in, const int* in_sizes, int n_in,
                              void* d_out, int out_size, void* d_ws, size_t ws_size,
                              hipStream_t stream) {
  const float* x   = (const float*)d_in[0];
  const int* edge  = (const int*)d_in[1];
  const float* W1  = (const float*)d_in[3];
  const float* b1  = (const float*)d_in[4];
  const float* W2  = (const float*)d_in[5];
  const float* b2  = (const float*)d_in[6];
  const float* W3  = (const float*)d_in[7];
  const float* b3  = (const float*)d_in[8];
  const float* Wp1 = (const float*)d_in[9];
  const float* bp1 = (const float*)d_in[10];
  const float* Wp2 = (const float*)d_in[11];
  const float* bp2 = (const float*)d_in[12];
  float* out = (float*)d_out;

  const int n = in_sizes[0] / NDIM_IN;   // 100000
  const int E = in_sizes[1] / 2;         // 1600000
  const int* src = edge;
  const int* dst = edge + E;

  // workspace carve-out (256B aligned slices)
  char* ws = (char*)d_ws;
  size_t off = 0;
  auto carve = [&](size_t bytes) {
    char* p = ws + off;
    off = (off + bytes + 255) & ~(size_t)255;
    return p;
  };
  int*    cnt   = (int*)carve((size_t)n * 4);
  float*  dinv  = (float*)carve((size_t)n * 4);
  int*    rp    = (int*)carve(((size_t)n + 1) * 4);
  int*    pos   = (int*)carve((size_t)n * 4);
  int*    bsum  = (int*)carve(512 * 4);
  int*    col   = (int*)carve((size_t)E * 4);
  __half* bufT  = (__half*)carve((size_t)n * HID * 2);
  float*  bufA  = (float*)carve((size_t)n * HID * 4);
  (void)ws_size; (void)n_in; (void)out_size;

  const int nbN = (n + 255) / 256;       // 391 (<=512 for scan2)
  const int slice_sz = (n + NS - 1) / NS;  // 12500
  const int nchunks = 512;               // 8*512 = 4096 blocks -> full occupancy

  hipMemsetAsync(cnt, 0, (size_t)n * 4, stream);
  count_deg<<<NS * nchunks, 256, 0, stream>>>(dst, cnt, E, slice_sz, nchunks);
  make_dinv<<<nbN, 256, 0, stream>>>(cnt, dinv, n);
  scan1<<<nbN, 256, 0, stream>>>(cnt, rp, bsum, n);
  scan2<<<1, 512, 0, stream>>>(bsum, nbN);
  scan3<<<nbN, 256, 0, stream>>>(rp, bsum, pos, n, E);
  fill_csr<<<NS * nchunks, 256, 0, stream>>>(src, dst, pos, col, E, slice_sz, nchunks);

  const int nbSp = ((n * 64) + 255) / 256;

  // layer 1: 128 -> 64
  gemm_xw<128><<<nbN, 256, 0, stream>>>(x, W1, dinv, bufT, n);
  spmm_relu<<<nbSp, 256, 0, stream>>>(rp, col, bufT, dinv, b1, bufA, n);
  // layer 2: 64 -> 64
  gemm_xw<64><<<nbN, 256, 0, stream>>>(bufA, W2, dinv, bufT, n);
  spmm_relu<<<nbSp, 256, 0, stream>>>(rp, col, bufT, dinv, b2, bufA, n);
  // layer 3: 64 -> 64
  gemm_xw<64><<<nbN, 256, 0, stream>>>(bufA, W3, dinv, bufT, n);
  spmm_relu<<<nbSp, 256, 0, stream>>>(rp, col, bufT, dinv, b3, bufA, n);
  // head
  mlp_head<<<nbN, 256, 0, stream>>>(bufA, Wp1, bp1, Wp2, bp2, out, n);
}

// Round 5
// 421.306 us; speedup vs baseline: 1.4108x; 1.4108x over previous
//
#include <hip/hip_runtime.h>
#include <hip/hip_bf16.h>
#include <hip/hip_fp16.h>

#define NDIM_IN 128
#define HID 64

#define BINW 128          // dst values per bin
#define NB   782          // ceil(100000/128)
#define NC   256          // phase-1 blocks
#define CAP  3072         // LDS edge buffer per bin (mean 2046, +22 sigma)

// ---------------------------------------------------------------------------
// Phase 1a: per-block LDS histogram over bins, written transposed:
// histT[bin*NC + block]. No global atomics, no memset needed.
// ---------------------------------------------------------------------------
__global__ __launch_bounds__(256) void hist_k(const int* __restrict__ dst,
                                              int* __restrict__ histT, int E) {
  __shared__ int h[NB];
  for (int i = threadIdx.x; i < NB; i += 256) h[i] = 0;
  __syncthreads();
  int E4 = E >> 2;
  int chunk = (E4 + NC - 1) / NC;
  int beg = blockIdx.x * chunk;
  int end = min(E4, beg + chunk);
  const int4* __restrict__ d4 = (const int4*)dst;
  for (int i = beg + (int)threadIdx.x; i < end; i += 256) {
    int4 d = d4[i];
    atomicAdd(&h[d.x >> 7], 1);
    atomicAdd(&h[d.y >> 7], 1);
    atomicAdd(&h[d.z >> 7], 1);
    atomicAdd(&h[d.w >> 7], 1);
  }
  __syncthreads();
  for (int i = threadIdx.x; i < NB; i += 256)
    histT[i * NC + blockIdx.x] = h[i];
}

// ---------------------------------------------------------------------------
// Flat exclusive scan of histT (NB*NC = 200192 elements, bin-major order ->
// scanned value IS the global scatter base for (bin, block)). In-place.
// ---------------------------------------------------------------------------
__global__ __launch_bounds__(256) void scan1(int* __restrict__ g,
                                             int* __restrict__ bs, int len) {
  __shared__ int s[256];
  int t = threadIdx.x;
  int i = blockIdx.x * 256 + t;
  int v = (i < len) ? g[i] : 0;
  s[t] = v;
  __syncthreads();
  for (int off = 1; off < 256; off <<= 1) {
    int x = (t >= off) ? s[t - off] : 0;
    __syncthreads();
    s[t] += x;
    __syncthreads();
  }
  if (i < len) g[i] = s[t] - v;          // exclusive within block
  if (t == 255) bs[blockIdx.x] = s[255];
}

__global__ __launch_bounds__(1024) void scan2(int* __restrict__ bs, int nb) {
  __shared__ int s[1024];
  int t = threadIdx.x;
  int v = (t < nb) ? bs[t] : 0;
  s[t] = v;
  __syncthreads();
  for (int off = 1; off < 1024; off <<= 1) {
    int x = (t >= off) ? s[t - off] : 0;
    __syncthreads();
    s[t] += x;
    __syncthreads();
  }
  if (t < nb) bs[t] = s[t] - v;
}

__global__ __launch_bounds__(256) void scan3(int* __restrict__ g,
                                             const int* __restrict__ boff, int len) {
  int i = blockIdx.x * 256 + threadIdx.x;
  if (i < len) g[i] += boff[blockIdx.x];
}

// ---------------------------------------------------------------------------
// Phase 1c: scatter (src,dst) pairs into tmp, grouped by bin. Positions come
// from LDS cursors seeded with the scanned global bases -> NO global atomics;
// same-bin edges from one block are contiguous (good write combining).
// ---------------------------------------------------------------------------
__global__ __launch_bounds__(256) void scatter_k(const int* __restrict__ src,
                                                 const int* __restrict__ dst,
                                                 const int* __restrict__ S,
                                                 int2* __restrict__ tmp, int E) {
  __shared__ int cur[NB];
  for (int i = threadIdx.x; i < NB; i += 256)
    cur[i] = S[i * NC + blockIdx.x];
  __syncthreads();
  int E4 = E >> 2;
  int chunk = (E4 + NC - 1) / NC;
  int beg = blockIdx.x * chunk;
  int end = min(E4, beg + chunk);
  const int4* __restrict__ d4 = (const int4*)dst;
  const int4* __restrict__ s4 = (const int4*)src;
  for (int i = beg + (int)threadIdx.x; i < end; i += 256) {
    int4 d = d4[i];
    int4 sv = s4[i];
    int p0 = atomicAdd(&cur[d.x >> 7], 1); tmp[p0] = make_int2(sv.x, d.x);
    int p1 = atomicAdd(&cur[d.y >> 7], 1); tmp[p1] = make_int2(sv.y, d.y);
    int p2 = atomicAdd(&cur[d.z >> 7], 1); tmp[p2] = make_int2(sv.z, d.z);
    int p3 = atomicAdd(&cur[d.w >> 7], 1); tmp[p3] = make_int2(sv.w, d.w);
  }
}

// ---------------------------------------------------------------------------
// Phase 2: one block per bin. Exact in-LDS counting sort by dst within the
// bin; emits col (coalesced), rp, and dinv. All atomics are LDS.
// ---------------------------------------------------------------------------
__global__ __launch_bounds__(256) void binsort_k(const int2* __restrict__ tmp,
                                                 const int* __restrict__ S,
                                                 int* __restrict__ col,
                                                 int* __restrict__ rp,
                                                 float* __restrict__ dinv,
                                                 int n, int E) {
  int bin = blockIdx.x;
  int base = S[bin * NC];
  int end = (bin == NB - 1) ? E : S[(bin + 1) * NC];
  int m = end - base;
  __shared__ int cnt[BINW];
  __shared__ int offs[BINW];
  __shared__ int cur[BINW];
  __shared__ int buf[CAP];
  int t = threadIdx.x;
  if (t < BINW) cnt[t] = 0;
  __syncthreads();
  for (int i = t; i < m; i += 256) {
    int2 e = tmp[base + i];
    atomicAdd(&cnt[e.y & (BINW - 1)], 1);
  }
  __syncthreads();
  if (t < BINW) offs[t] = cnt[t];
  __syncthreads();
  for (int off = 1; off < BINW; off <<= 1) {
    int x = (t < BINW && t >= off) ? offs[t - off] : 0;
    __syncthreads();
    if (t < BINW) offs[t] += x;
    __syncthreads();
  }
  if (t < BINW) {
    int ex = offs[t] - cnt[t];             // exclusive
    cur[t] = ex;
    int v = bin * BINW + t;
    if (v < n) {
      rp[v] = base + ex;
      dinv[v] = rsqrtf((float)cnt[t] + 1.0f);  // +1 = self loop
    }
  }
  if (bin == NB - 1 && t == 0) rp[n] = E;
  __syncthreads();
  for (int i = t; i < m; i += 256) {
    int2 e = tmp[base + i];
    int r = atomicAdd(&cur[e.y & (BINW - 1)], 1);
    if (r < CAP) buf[r] = e.x;
  }
  __syncthreads();
  int mm = min(m, CAP);
  for (int i = t; i < mm; i += 256) col[base + i] = buf[i];
}

// ---------------------------------------------------------------------------
// Dense transform T' = (X @ W) * dinv[row], output fp16 (halves gather bytes)
// dinv fold: msg(s->d) = T[s]*dinv[s]*dinv[d]  =>  agg[d] = dinv[d]*Σ T'[col]
// ---------------------------------------------------------------------------
template <int K>
__global__ __launch_bounds__(256) void gemm_xw(const float* __restrict__ X,
                                               const float* __restrict__ W,
                                               const float* __restrict__ dinv,
                                               __half* __restrict__ T, int n) {
  __shared__ float Ws[K * 64];
  for (int i = threadIdx.x; i < K * 64; i += 256) Ws[i] = W[i];
  __syncthreads();
  int node = blockIdx.x * 256 + threadIdx.x;
  if (node >= n) return;
  float4 acc[16];
#pragma unroll
  for (int j = 0; j < 16; j++) acc[j] = make_float4(0.f, 0.f, 0.f, 0.f);
  const float4* __restrict__ xr = (const float4*)(X + (size_t)node * K);
#pragma unroll
  for (int kc = 0; kc < K / 4; kc++) {
    float4 xv = xr[kc];
    float xs[4] = {xv.x, xv.y, xv.z, xv.w};
#pragma unroll
    for (int kk = 0; kk < 4; kk++) {
      float xk = xs[kk];
      const float4* wr = (const float4*)(Ws + (kc * 4 + kk) * 64);
#pragma unroll
      for (int j = 0; j < 16; j++) {
        float4 w = wr[j];
        acc[j].x += xk * w.x;
        acc[j].y += xk * w.y;
        acc[j].z += xk * w.z;
        acc[j].w += xk * w.w;
      }
    }
  }
  float di = dinv[node];
  uint2* __restrict__ o = (uint2*)(T + (size_t)node * 64);
#pragma unroll
  for (int j = 0; j < 16; j++) {
    __half2 h01 = __floats2half2_rn(acc[j].x * di, acc[j].y * di);
    __half2 h23 = __floats2half2_rn(acc[j].z * di, acc[j].w * di);
    uint2 pk;
    pk.x = *(unsigned int*)&h01;
    pk.y = *(unsigned int*)&h23;
    o[j] = pk;
  }
}

// ---------------------------------------------------------------------------
// SpMM gather, 2 edges per wave: lanes 0-31 = even edge, 32-63 = odd edge,
// each lane loads uint2 (2 fp16 features). 4 chains x 2 = 8 gathers in
// flight. Epilogue: xor-shuffle across halves + lane remap.
// ---------------------------------------------------------------------------
__global__ __launch_bounds__(256) void spmm_relu(const int* __restrict__ rp,
                                                 const int* __restrict__ col,
                                                 const __half* __restrict__ T,
                                                 const float* __restrict__ dinv,
                                                 const float* __restrict__ bias,
                                                 float* __restrict__ H, int n) {
  int gid = blockIdx.x * 256 + threadIdx.x;
  int v = gid >> 6;
  int lane = gid & 63;
  if (v >= n) return;
  int beg = rp[v], end = rp[v + 1];
  int half = lane >> 5, sub = lane & 31;
  const unsigned int* __restrict__ T32 = (const unsigned int*)T;  // 32 uints/row

  float2 a0 = {0.f, 0.f}, a1 = {0.f, 0.f}, a2 = {0.f, 0.f}, a3 = {0.f, 0.f};
  {  // self loop: add once (half 0 only)
    unsigned int w = T32[(size_t)v * 32 + sub];
    __half2 h2 = *(__half2*)&w;
    float2 f = __half22float2(h2);
    if (half == 0) { a0.x += f.x; a0.y += f.y; }
  }
  int last = end - 1;
  for (int e = beg; e < end; e += 8) {
    int i0 = e + half, i1 = e + 2 + half, i2 = e + 4 + half, i3 = e + 6 + half;
    int s0 = col[min(i0, last)];
    int s1 = col[min(i1, last)];
    int s2 = col[min(i2, last)];
    int s3 = col[min(i3, last)];
    unsigned int w0 = T32[(size_t)s0 * 32 + sub];
    unsigned int w1 = T32[(size_t)s1 * 32 + sub];
    unsigned int w2 = T32[(size_t)s2 * 32 + sub];
    unsigned int w3 = T32[(size_t)s3 * 32 + sub];
    float2 f0 = __half22float2(*(__half2*)&w0);
    float2 f1 = __half22float2(*(__half2*)&w1);
    float2 f2 = __half22float2(*(__half2*)&w2);
    float2 f3 = __half22float2(*(__half2*)&w3);
    a0.x += (i0 < end) ? f0.x : 0.f;  a0.y += (i0 < end) ? f0.y : 0.f;
    a1.x += (i1 < end) ? f1.x : 0.f;  a1.y += (i1 < end) ? f1.y : 0.f;
    a2.x += (i2 < end) ? f2.x : 0.f;  a2.y += (i2 < end) ? f2.y : 0.f;
    a3.x += (i3 < end) ? f3.x : 0.f;  a3.y += (i3 < end) ? f3.y : 0.f;
  }
  float sx = a0.x + a1.x + a2.x + a3.x;
  float sy = a0.y + a1.y + a2.y + a3.y;
  sx += __shfl_xor(sx, 32);  // combine even/odd edge halves
  sy += __shfl_xor(sy, 32);
  // remap: feature `lane` = component (lane&1) of pair lane>>1
  int srcl = lane >> 1;
  float vx = __shfl(sx, srcl);
  float vy = __shfl(sy, srcl);
  float val = (lane & 1) ? vy : vx;
  float r = dinv[v] * val + bias[lane];
  H[(size_t)v * HID + lane] = r > 0.f ? r : 0.f;
}

// ---------------------------------------------------------------------------
// Fused MLP head: out = relu(H @ Wp1 + bp1) @ Wp2 + bp2, thread-per-node
// ---------------------------------------------------------------------------
__global__ __launch_bounds__(256) void mlp_head(const float* __restrict__ H,
                                                const float* __restrict__ Wp1,
                                                const float* __restrict__ bp1,
                                                const float* __restrict__ Wp2,
                                                const float* __restrict__ bp2,
                                                float* __restrict__ out, int n) {
  __shared__ float W1t[32 * 64];  // transposed: W1t[j*64+k] = Wp1[k*32+j]
  __shared__ float w2s[32];
  __shared__ float b1s[32];
  for (int i = threadIdx.x; i < 64 * 32; i += 256) {
    int k = i >> 5, j = i & 31;
    W1t[j * 64 + k] = Wp1[i];
  }
  if (threadIdx.x < 32) {
    w2s[threadIdx.x] = Wp2[threadIdx.x];
    b1s[threadIdx.x] = bp1[threadIdx.x];
  }
  __syncthreads();
  int node = blockIdx.x * 256 + threadIdx.x;
  if (node >= n) return;
  float4 h[16];
  const float4* __restrict__ hr = (const float4*)(H + (size_t)node * 64);
#pragma unroll
  for (int j = 0; j < 16; j++) h[j] = hr[j];
  float o = bp2[0];
#pragma unroll
  for (int j = 0; j < 32; j++) {
    const float4* wr = (const float4*)(W1t + j * 64);
    float4 a4 = make_float4(0.f, 0.f, 0.f, 0.f);
#pragma unroll
    for (int k = 0; k < 16; k++) {
      float4 w = wr[k];
      a4.x += h[k].x * w.x;
      a4.y += h[k].y * w.y;
      a4.z += h[k].z * w.z;
      a4.w += h[k].w * w.w;
    }
    float a = a4.x + a4.y + a4.z + a4.w + b1s[j];
    a = a > 0.f ? a : 0.f;
    o += a * w2s[j];
  }
  out[node] = o;
}

// ---------------------------------------------------------------------------
extern "C" void kernel_launch(void* const* d_in, const int* in_sizes, int n_in,
                              void* d_out, int out_size, void* d_ws, size_t ws_size,
                              hipStream_t stream) {
  const float* x   = (const float*)d_in[0];
  const int* edge  = (const int*)d_in[1];
  const float* W1  = (const float*)d_in[3];
  const float* b1  = (const float*)d_in[4];
  const float* W2  = (const float*)d_in[5];
  const float* b2  = (const float*)d_in[6];
  const float* W3  = (const float*)d_in[7];
  const float* b3  = (const float*)d_in[8];
  const float* Wp1 = (const float*)d_in[9];
  const float* bp1 = (const float*)d_in[10];
  const float* Wp2 = (const float*)d_in[11];
  const float* bp2 = (const float*)d_in[12];
  float* out = (float*)d_out;

  const int n = in_sizes[0] / NDIM_IN;   // 100000
  const int E = in_sizes[1] / 2;         // 1600000
  const int* src = edge;
  const int* dst = edge + E;

  // workspace carve-out (256B aligned slices)
  char* ws = (char*)d_ws;
  size_t off = 0;
  auto carve = [&](size_t bytes) {
    char* p = ws + off;
    off = (off + bytes + 255) & ~(size_t)255;
    return p;
  };
  int*    histT = (int*)carve((size_t)NB * NC * 4);   // 800 KB
  int*    bsum  = (int*)carve(1024 * 4);
  int2*   tmp   = (int2*)carve((size_t)E * 8);        // 12.8 MB
  int*    col   = (int*)carve((size_t)E * 4);         // 6.4 MB
  int*    rp    = (int*)carve(((size_t)n + 1) * 4);
  float*  dinv  = (float*)carve((size_t)n * 4);
  __half* bufT  = (__half*)carve((size_t)n * HID * 2);
  float*  bufA  = (float*)carve((size_t)n * HID * 4);
  (void)ws_size; (void)n_in; (void)out_size;

  const int nbN = (n + 255) / 256;        // 391
  const int scan_len = NB * NC;           // 200192
  const int nbScan = (scan_len + 255) / 256;  // 782 (<=1024 for scan2)

  hist_k<<<NC, 256, 0, stream>>>(dst, histT, E);
  scan1<<<nbScan, 256, 0, stream>>>(histT, bsum, scan_len);
  scan2<<<1, 1024, 0, stream>>>(bsum, nbScan);
  scan3<<<nbScan, 256, 0, stream>>>(histT, bsum, scan_len);
  scatter_k<<<NC, 256, 0, stream>>>(src, dst, histT, tmp, E);
  binsort_k<<<NB, 256, 0, stream>>>(tmp, histT, col, rp, dinv, n, E);

  const int nbSp = ((n * 64) + 255) / 256;

  // layer 1: 128 -> 64
  gemm_xw<128><<<nbN, 256, 0, stream>>>(x, W1, dinv, bufT, n);
  spmm_relu<<<nbSp, 256, 0, stream>>>(rp, col, bufT, dinv, b1, bufA, n);
  // layer 2: 64 -> 64
  gemm_xw<64><<<nbN, 256, 0, stream>>>(bufA, W2, dinv, bufT, n);
  spmm_relu<<<nbSp, 256, 0, stream>>>(rp, col, bufT, dinv, b2, bufA, n);
  // layer 3: 64 -> 64
  gemm_xw<64><<<nbN, 256, 0, stream>>>(bufA, W3, dinv, bufT, n);
  spmm_relu<<<nbSp, 256, 0, stream>>>(rp, col, bufT, dinv, b3, bufA, n);
  // head
  mlp_head<<<nbN, 256, 0, stream>>>(bufA, Wp1, bp1, Wp2, bp2, out, n);
}

// Round 6
// 356.586 us; speedup vs baseline: 1.6669x; 1.1815x over previous
//
#include <hip/hip_runtime.h>
#include <hip/hip_bf16.h>
#include <hip/hip_fp16.h>

#define NDIM_IN 128
#define HID 64

#define BINW 128          // dst values per bin
#define NB   782          // ceil(100000/128)
#define NC   256          // phase-1 blocks
#define CAP  3072         // LDS edge buffer per bin (mean 2046, +22 sigma)

// ---------------------------------------------------------------------------
// Phase 1a: per-block LDS histogram over bins, written transposed:
// histT[bin*NC + block]. No global atomics, no memset needed.
// ---------------------------------------------------------------------------
__global__ __launch_bounds__(256) void hist_k(const int* __restrict__ dst,
                                              int* __restrict__ histT, int E) {
  __shared__ int h[NB];
  for (int i = threadIdx.x; i < NB; i += 256) h[i] = 0;
  __syncthreads();
  int E4 = E >> 2;
  int chunk = (E4 + NC - 1) / NC;
  int beg = blockIdx.x * chunk;
  int end = min(E4, beg + chunk);
  const int4* __restrict__ d4 = (const int4*)dst;
  for (int i = beg + (int)threadIdx.x; i < end; i += 256) {
    int4 d = d4[i];
    atomicAdd(&h[d.x >> 7], 1);
    atomicAdd(&h[d.y >> 7], 1);
    atomicAdd(&h[d.z >> 7], 1);
    atomicAdd(&h[d.w >> 7], 1);
  }
  __syncthreads();
  for (int i = threadIdx.x; i < NB; i += 256)
    histT[i * NC + blockIdx.x] = h[i];
}

// ---------------------------------------------------------------------------
// Flat exclusive scan of histT (NB*NC = 200192 elements, bin-major order ->
// scanned value IS the global scatter base for (bin, block)). In-place.
// ---------------------------------------------------------------------------
__global__ __launch_bounds__(256) void scan1(int* __restrict__ g,
                                             int* __restrict__ bs, int len) {
  __shared__ int s[256];
  int t = threadIdx.x;
  int i = blockIdx.x * 256 + t;
  int v = (i < len) ? g[i] : 0;
  s[t] = v;
  __syncthreads();
  for (int off = 1; off < 256; off <<= 1) {
    int x = (t >= off) ? s[t - off] : 0;
    __syncthreads();
    s[t] += x;
    __syncthreads();
  }
  if (i < len) g[i] = s[t] - v;          // exclusive within block
  if (t == 255) bs[blockIdx.x] = s[255];
}

__global__ __launch_bounds__(1024) void scan2(int* __restrict__ bs, int nb) {
  __shared__ int s[1024];
  int t = threadIdx.x;
  int v = (t < nb) ? bs[t] : 0;
  s[t] = v;
  __syncthreads();
  for (int off = 1; off < 1024; off <<= 1) {
    int x = (t >= off) ? s[t - off] : 0;
    __syncthreads();
    s[t] += x;
    __syncthreads();
  }
  if (t < nb) bs[t] = s[t] - v;
}

__global__ __launch_bounds__(256) void scan3(int* __restrict__ g,
                                             const int* __restrict__ boff, int len) {
  int i = blockIdx.x * 256 + threadIdx.x;
  if (i < len) g[i] += boff[blockIdx.x];
}

// ---------------------------------------------------------------------------
// Phase 1c: scatter (src,dst) pairs into tmp, grouped by bin. Positions come
// from LDS cursors seeded with the scanned global bases -> NO global atomics;
// same-bin edges from one block are contiguous (good write combining).
// ---------------------------------------------------------------------------
__global__ __launch_bounds__(256) void scatter_k(const int* __restrict__ src,
                                                 const int* __restrict__ dst,
                                                 const int* __restrict__ S,
                                                 int2* __restrict__ tmp, int E) {
  __shared__ int cur[NB];
  for (int i = threadIdx.x; i < NB; i += 256)
    cur[i] = S[i * NC + blockIdx.x];
  __syncthreads();
  int E4 = E >> 2;
  int chunk = (E4 + NC - 1) / NC;
  int beg = blockIdx.x * chunk;
  int end = min(E4, beg + chunk);
  const int4* __restrict__ d4 = (const int4*)dst;
  const int4* __restrict__ s4 = (const int4*)src;
  for (int i = beg + (int)threadIdx.x; i < end; i += 256) {
    int4 d = d4[i];
    int4 sv = s4[i];
    int p0 = atomicAdd(&cur[d.x >> 7], 1); tmp[p0] = make_int2(sv.x, d.x);
    int p1 = atomicAdd(&cur[d.y >> 7], 1); tmp[p1] = make_int2(sv.y, d.y);
    int p2 = atomicAdd(&cur[d.z >> 7], 1); tmp[p2] = make_int2(sv.z, d.z);
    int p3 = atomicAdd(&cur[d.w >> 7], 1); tmp[p3] = make_int2(sv.w, d.w);
  }
}

// ---------------------------------------------------------------------------
// Phase 2: one block per bin. Exact in-LDS counting sort by dst within the
// bin; emits col (coalesced), rp, and dinv. All atomics are LDS.
// ---------------------------------------------------------------------------
__global__ __launch_bounds__(256) void binsort_k(const int2* __restrict__ tmp,
                                                 const int* __restrict__ S,
                                                 int* __restrict__ col,
                                                 int* __restrict__ rp,
                                                 float* __restrict__ dinv,
                                                 int n, int E) {
  int bin = blockIdx.x;
  int base = S[bin * NC];
  int end = (bin == NB - 1) ? E : S[(bin + 1) * NC];
  int m = end - base;
  __shared__ int cnt[BINW];
  __shared__ int offs[BINW];
  __shared__ int cur[BINW];
  __shared__ int buf[CAP];
  int t = threadIdx.x;
  if (t < BINW) cnt[t] = 0;
  __syncthreads();
  for (int i = t; i < m; i += 256) {
    int2 e = tmp[base + i];
    atomicAdd(&cnt[e.y & (BINW - 1)], 1);
  }
  __syncthreads();
  if (t < BINW) offs[t] = cnt[t];
  __syncthreads();
  for (int off = 1; off < BINW; off <<= 1) {
    int x = (t < BINW && t >= off) ? offs[t - off] : 0;
    __syncthreads();
    if (t < BINW) offs[t] += x;
    __syncthreads();
  }
  if (t < BINW) {
    int ex = offs[t] - cnt[t];             // exclusive
    cur[t] = ex;
    int v = bin * BINW + t;
    if (v < n) {
      rp[v] = base + ex;
      dinv[v] = rsqrtf((float)cnt[t] + 1.0f);  // +1 = self loop
    }
  }
  if (bin == NB - 1 && t == 0) rp[n] = E;
  __syncthreads();
  for (int i = t; i < m; i += 256) {
    int2 e = tmp[base + i];
    int r = atomicAdd(&cur[e.y & (BINW - 1)], 1);
    if (r < CAP) buf[r] = e.x;
  }
  __syncthreads();
  int mm = min(m, CAP);
  for (int i = t; i < mm; i += 256) col[base + i] = buf[i];
}

// ---------------------------------------------------------------------------
// Dense transform T' = (X @ W) * dinv[row], output fp16.
// Block = 256 threads = 64 nodes x 4 out-groups (og wave-uniform; 16 outs).
// X staged in LDS (stride K+1, conflict-free b32 reads); W read via wave-
// uniform addresses -> s_load into SGPRs (scalar pipe, zero LDS/VGPR cost).
// 1563 blocks -> ~6 waves/SIMD (vs 1.5 in thread-per-node version).
// ---------------------------------------------------------------------------
template <int K>
__global__ __launch_bounds__(256) void gemm_xw(const float* __restrict__ X,
                                               const float* __restrict__ W,
                                               const float* __restrict__ dinv,
                                               __half* __restrict__ T, int n) {
  constexpr int STR = K + 1;
  constexpr int RF4 = K / 4;  // float4 per row
  __shared__ float Xs[64 * STR];
  int t = threadIdx.x;
  int node0 = blockIdx.x * 64;
  for (int i = t; i < 64 * RF4; i += 256) {
    int r = i / RF4, c = i % RF4;
    int node = node0 + r;
    float4 v = make_float4(0.f, 0.f, 0.f, 0.f);
    if (node < n) v = *(const float4*)(X + (size_t)node * K + c * 4);
    float* p = &Xs[r * STR + c * 4];
    p[0] = v.x; p[1] = v.y; p[2] = v.z; p[3] = v.w;
  }
  __syncthreads();
  int lane = t & 63;
  int og = __builtin_amdgcn_readfirstlane(t >> 6);  // wave-uniform out-group
  int node = node0 + lane;
  const float* __restrict__ Wg = W + og * 16;       // uniform -> s_load
  const float* __restrict__ xrow = &Xs[lane * STR];
  float4 a0 = make_float4(0.f, 0.f, 0.f, 0.f);
  float4 a1 = make_float4(0.f, 0.f, 0.f, 0.f);
  float4 a2 = make_float4(0.f, 0.f, 0.f, 0.f);
  float4 a3 = make_float4(0.f, 0.f, 0.f, 0.f);
#pragma unroll 4
  for (int k = 0; k < K; k++) {
    float xk = xrow[k];
    const float* __restrict__ wk = Wg + k * 64;
    a0.x += xk * wk[0];  a0.y += xk * wk[1];  a0.z += xk * wk[2];  a0.w += xk * wk[3];
    a1.x += xk * wk[4];  a1.y += xk * wk[5];  a1.z += xk * wk[6];  a1.w += xk * wk[7];
    a2.x += xk * wk[8];  a2.y += xk * wk[9];  a2.z += xk * wk[10]; a2.w += xk * wk[11];
    a3.x += xk * wk[12]; a3.y += xk * wk[13]; a3.z += xk * wk[14]; a3.w += xk * wk[15];
  }
  if (node >= n) return;
  float di = dinv[node];
  __half2 h0 = __floats2half2_rn(a0.x * di, a0.y * di);
  __half2 h1 = __floats2half2_rn(a0.z * di, a0.w * di);
  __half2 h2 = __floats2half2_rn(a1.x * di, a1.y * di);
  __half2 h3 = __floats2half2_rn(a1.z * di, a1.w * di);
  __half2 h4 = __floats2half2_rn(a2.x * di, a2.y * di);
  __half2 h5 = __floats2half2_rn(a2.z * di, a2.w * di);
  __half2 h6 = __floats2half2_rn(a3.x * di, a3.y * di);
  __half2 h7 = __floats2half2_rn(a3.z * di, a3.w * di);
  uint4* __restrict__ o = (uint4*)(T + (size_t)node * 64 + og * 16);
  uint4 p0, p1;
  p0.x = *(unsigned int*)&h0; p0.y = *(unsigned int*)&h1;
  p0.z = *(unsigned int*)&h2; p0.w = *(unsigned int*)&h3;
  p1.x = *(unsigned int*)&h4; p1.y = *(unsigned int*)&h5;
  p1.z = *(unsigned int*)&h6; p1.w = *(unsigned int*)&h7;
  o[0] = p0;
  o[1] = p1;
}

// ---------------------------------------------------------------------------
// SpMM gather, 2 edges per wave: lanes 0-31 = even edge, 32-63 = odd edge,
// each lane loads uint2 (2 fp16 features). 4 chains x 2 = 8 gathers in
// flight. Epilogue: xor-shuffle across halves + lane remap.
// ---------------------------------------------------------------------------
__global__ __launch_bounds__(256) void spmm_relu(const int* __restrict__ rp,
                                                 const int* __restrict__ col,
                                                 const __half* __restrict__ T,
                                                 const float* __restrict__ dinv,
                                                 const float* __restrict__ bias,
                                                 float* __restrict__ H, int n) {
  int gid = blockIdx.x * 256 + threadIdx.x;
  int v = gid >> 6;
  int lane = gid & 63;
  if (v >= n) return;
  int beg = rp[v], end = rp[v + 1];
  int half = lane >> 5, sub = lane & 31;
  const unsigned int* __restrict__ T32 = (const unsigned int*)T;  // 32 uints/row

  float2 a0 = {0.f, 0.f}, a1 = {0.f, 0.f}, a2 = {0.f, 0.f}, a3 = {0.f, 0.f};
  {  // self loop: add once (half 0 only)
    unsigned int w = T32[(size_t)v * 32 + sub];
    __half2 h2 = *(__half2*)&w;
    float2 f = __half22float2(h2);
    if (half == 0) { a0.x += f.x; a0.y += f.y; }
  }
  int last = end - 1;
  for (int e = beg; e < end; e += 8) {
    int i0 = e + half, i1 = e + 2 + half, i2 = e + 4 + half, i3 = e + 6 + half;
    int s0 = col[min(i0, last)];
    int s1 = col[min(i1, last)];
    int s2 = col[min(i2, last)];
    int s3 = col[min(i3, last)];
    unsigned int w0 = T32[(size_t)s0 * 32 + sub];
    unsigned int w1 = T32[(size_t)s1 * 32 + sub];
    unsigned int w2 = T32[(size_t)s2 * 32 + sub];
    unsigned int w3 = T32[(size_t)s3 * 32 + sub];
    float2 f0 = __half22float2(*(__half2*)&w0);
    float2 f1 = __half22float2(*(__half2*)&w1);
    float2 f2 = __half22float2(*(__half2*)&w2);
    float2 f3 = __half22float2(*(__half2*)&w3);
    a0.x += (i0 < end) ? f0.x : 0.f;  a0.y += (i0 < end) ? f0.y : 0.f;
    a1.x += (i1 < end) ? f1.x : 0.f;  a1.y += (i1 < end) ? f1.y : 0.f;
    a2.x += (i2 < end) ? f2.x : 0.f;  a2.y += (i2 < end) ? f2.y : 0.f;
    a3.x += (i3 < end) ? f3.x : 0.f;  a3.y += (i3 < end) ? f3.y : 0.f;
  }
  float sx = a0.x + a1.x + a2.x + a3.x;
  float sy = a0.y + a1.y + a2.y + a3.y;
  sx += __shfl_xor(sx, 32);  // combine even/odd edge halves
  sy += __shfl_xor(sy, 32);
  // remap: feature `lane` = component (lane&1) of pair lane>>1
  int srcl = lane >> 1;
  float vx = __shfl(sx, srcl);
  float vy = __shfl(sy, srcl);
  float val = (lane & 1) ? vy : vx;
  float r = dinv[v] * val + bias[lane];
  H[(size_t)v * HID + lane] = r > 0.f ? r : 0.f;
}

// ---------------------------------------------------------------------------
// Fused MLP head: out = relu(H @ Wp1 + bp1) @ Wp2 + bp2, thread-per-node
// ---------------------------------------------------------------------------
__global__ __launch_bounds__(256) void mlp_head(const float* __restrict__ H,
                                                const float* __restrict__ Wp1,
                                                const float* __restrict__ bp1,
                                                const float* __restrict__ Wp2,
                                                const float* __restrict__ bp2,
                                                float* __restrict__ out, int n) {
  __shared__ float W1t[32 * 64];  // transposed: W1t[j*64+k] = Wp1[k*32+j]
  __shared__ float w2s[32];
  __shared__ float b1s[32];
  for (int i = threadIdx.x; i < 64 * 32; i += 256) {
    int k = i >> 5, j = i & 31;
    W1t[j * 64 + k] = Wp1[i];
  }
  if (threadIdx.x < 32) {
    w2s[threadIdx.x] = Wp2[threadIdx.x];
    b1s[threadIdx.x] = bp1[threadIdx.x];
  }
  __syncthreads();
  int node = blockIdx.x * 256 + threadIdx.x;
  if (node >= n) return;
  float4 h[16];
  const float4* __restrict__ hr = (const float4*)(H + (size_t)node * 64);
#pragma unroll
  for (int j = 0; j < 16; j++) h[j] = hr[j];
  float o = bp2[0];
#pragma unroll
  for (int j = 0; j < 32; j++) {
    const float4* wr = (const float4*)(W1t + j * 64);
    float4 a4 = make_float4(0.f, 0.f, 0.f, 0.f);
#pragma unroll
    for (int k = 0; k < 16; k++) {
      float4 w = wr[k];
      a4.x += h[k].x * w.x;
      a4.y += h[k].y * w.y;
      a4.z += h[k].z * w.z;
      a4.w += h[k].w * w.w;
    }
    float a = a4.x + a4.y + a4.z + a4.w + b1s[j];
    a = a > 0.f ? a : 0.f;
    o += a * w2s[j];
  }
  out[node] = o;
}

// ---------------------------------------------------------------------------
extern "C" void kernel_launch(void* const* d_in, const int* in_sizes, int n_in,
                              void* d_out, int out_size, void* d_ws, size_t ws_size,
                              hipStream_t stream) {
  const float* x   = (const float*)d_in[0];
  const int* edge  = (const int*)d_in[1];
  const float* W1  = (const float*)d_in[3];
  const float* b1  = (const float*)d_in[4];
  const float* W2  = (const float*)d_in[5];
  const float* b2  = (const float*)d_in[6];
  const float* W3  = (const float*)d_in[7];
  const float* b3  = (const float*)d_in[8];
  const float* Wp1 = (const float*)d_in[9];
  const float* bp1 = (const float*)d_in[10];
  const float* Wp2 = (const float*)d_in[11];
  const float* bp2 = (const float*)d_in[12];
  float* out = (float*)d_out;

  const int n = in_sizes[0] / NDIM_IN;   // 100000
  const int E = in_sizes[1] / 2;         // 1600000
  const int* src = edge;
  const int* dst = edge + E;

  // workspace carve-out (256B aligned slices)
  char* ws = (char*)d_ws;
  size_t off = 0;
  auto carve = [&](size_t bytes) {
    char* p = ws + off;
    off = (off + bytes + 255) & ~(size_t)255;
    return p;
  };
  int*    histT = (int*)carve((size_t)NB * NC * 4);   // 800 KB
  int*    bsum  = (int*)carve(1024 * 4);
  int2*   tmp   = (int2*)carve((size_t)E * 8);        // 12.8 MB
  int*    col   = (int*)carve((size_t)E * 4);         // 6.4 MB
  int*    rp    = (int*)carve(((size_t)n + 1) * 4);
  float*  dinv  = (float*)carve((size_t)n * 4);
  __half* bufT  = (__half*)carve((size_t)n * HID * 2);
  float*  bufA  = (float*)carve((size_t)n * HID * 4);
  (void)ws_size; (void)n_in; (void)out_size;

  const int nbN = (n + 255) / 256;        // 391
  const int nbG = (n + 63) / 64;          // 1563 (gemm: 64 nodes/block)
  const int scan_len = NB * NC;           // 200192
  const int nbScan = (scan_len + 255) / 256;  // 782 (<=1024 for scan2)

  hist_k<<<NC, 256, 0, stream>>>(dst, histT, E);
  scan1<<<nbScan, 256, 0, stream>>>(histT, bsum, scan_len);
  scan2<<<1, 1024, 0, stream>>>(bsum, nbScan);
  scan3<<<nbScan, 256, 0, stream>>>(histT, bsum, scan_len);
  scatter_k<<<NC, 256, 0, stream>>>(src, dst, histT, tmp, E);
  binsort_k<<<NB, 256, 0, stream>>>(tmp, histT, col, rp, dinv, n, E);

  const int nbSp = ((n * 64) + 255) / 256;

  // layer 1: 128 -> 64
  gemm_xw<128><<<nbG, 256, 0, stream>>>(x, W1, dinv, bufT, n);
  spmm_relu<<<nbSp, 256, 0, stream>>>(rp, col, bufT, dinv, b1, bufA, n);
  // layer 2: 64 -> 64
  gemm_xw<64><<<nbG, 256, 0, stream>>>(bufA, W2, dinv, bufT, n);
  spmm_relu<<<nbSp, 256, 0, stream>>>(rp, col, bufT, dinv, b2, bufA, n);
  // layer 3: 64 -> 64
  gemm_xw<64><<<nbG, 256, 0, stream>>>(bufA, W3, dinv, bufT, n);
  spmm_relu<<<nbSp, 256, 0, stream>>>(rp, col, bufT, dinv, b3, bufA, n);
  // head
  mlp_head<<<nbN, 256, 0, stream>>>(bufA, Wp1, bp1, Wp2, bp2, out, n);
}